// Round 5
// baseline (126.306 us; speedup 1.0000x reference)
//
#include <hip/hip_runtime.h>
#include <hip/hip_bf16.h>
#include <cstdio>

// Problem constants: B=2, S=1024, D=256, H=8, K=32
#define PB 2
#define PS 1024
#define PD 256
#define PK 32
#define PH 8
#define HB (PH*PB)          // 16
#define BS (PB*PS)          // 2048
#define EPS 1e-9f

typedef __attribute__((ext_vector_type(8))) short bf16x8;
typedef __attribute__((ext_vector_type(4))) float f32x4;

__device__ inline unsigned short f2bf(float f) {
    __hip_bfloat16 h = __float2bfloat16(f);
    return *reinterpret_cast<unsigned short*>(&h);
}

// ---------------- kernel A: x -> bf16 ---------------------------------------
__global__ void k_xb(const float* __restrict__ x, unsigned short* __restrict__ xb) {
    int i = blockIdx.x*256 + threadIdx.x;       // 131072 float4s
    float4 v = ((const float4*)x)[i];
    ushort4 o = {f2bf(v.x), f2bf(v.y), f2bf(v.z), f2bf(v.w)};
    ((ushort4*)xb)[i] = o;
}

// ---------------- kernel B: Wq/Wk [h][d 256][kk 32] -> [h][kk][d] bf16 ------
__global__ void k_transpose_qk(const float* __restrict__ Wqs, const float* __restrict__ Wks,
                               unsigned short* __restrict__ WqT, unsigned short* __restrict__ WkT) {
    int h = blockIdx.x;
    const float* S = (blockIdx.y ? Wks : Wqs) + (size_t)h*8192;
    unsigned short* D = (blockIdx.y ? WkT : WqT) + (size_t)h*8192;
    __shared__ float T[256*33];
    int tid = threadIdx.x;
#pragma unroll
    for (int p = 0; p < 32; ++p) {
        int idx = p*256 + tid;                  // d*32 + kk
        T[(idx>>5)*33 + (idx&31)] = S[idx];
    }
    __syncthreads();
#pragma unroll
    for (int p = 0; p < 8; ++p) {
        int o4 = p*256 + tid;                   // ushort4 idx: flat = kk*256 + d
        int kk = o4 >> 6, d = (o4 & 63)*4;
        ushort4 o;
        o.x = f2bf(T[(d+0)*33 + kk]); o.y = f2bf(T[(d+1)*33 + kk]);
        o.z = f2bf(T[(d+2)*33 + kk]); o.w = f2bf(T[(d+3)*33 + kk]);
        *(ushort4*)(D + (size_t)kk*256 + d) = o;
    }
}

// ---------------- kernel C: 256x256 per-head transpose f32 -> bf16 ----------
// dst(h, e, d) = src(h, d, e);  dst addr = h*head_stride + e*row_stride + d
__global__ void k_transpose256(const float* __restrict__ src, unsigned short* __restrict__ dst,
                               int dst_row_stride, int dst_head_stride) {
    int e0 = blockIdx.x*64, d0 = blockIdx.y*64, h = blockIdx.z;
    __shared__ float T[64][69];
    const float* S = src + (size_t)h*65536;
    int ty = threadIdx.x>>4, c4 = threadIdx.x&15;
#pragma unroll
    for (int p = 0; p < 4; ++p) {
        int r = p*16 + ty;                      // d row
        float4 v = *(const float4*)(S + (size_t)(d0+r)*256 + e0 + c4*4);
        T[r][c4*4+0]=v.x; T[r][c4*4+1]=v.y; T[r][c4*4+2]=v.z; T[r][c4*4+3]=v.w;
    }
    __syncthreads();
    unsigned short* D = dst + (size_t)h*dst_head_stride;
#pragma unroll
    for (int p = 0; p < 4; ++p) {
        int er = p*16 + ty;                     // e row
        ushort4 o;
        o.x = f2bf(T[c4*4+0][er]); o.y = f2bf(T[c4*4+1][er]);
        o.z = f2bf(T[c4*4+2][er]); o.w = f2bf(T[c4*4+3][er]);
        *(ushort4*)(D + (size_t)(e0+er)*dst_row_stride + d0 + c4*4) = o;
    }
}

// ---------------- kernel 1: Q/K projection via MFMA + elu+1 ------------------
__global__ __launch_bounds__(256) void k_proj_qk_mfma(
    const unsigned short* __restrict__ xb, const unsigned short* __restrict__ WqT,
    const unsigned short* __restrict__ WkT,
    float* __restrict__ Q, float* __restrict__ Kf,
    unsigned short* __restrict__ Qb, unsigned short* __restrict__ Kb)
{
    int m0 = blockIdx.x*64;
    int isK = blockIdx.y;
    int n0 = blockIdx.z*64;
    const unsigned short* W = isK ? WkT : WqT;
    int tid = threadIdx.x, w = tid>>6, l15 = tid&15, g = (tid>>4)&3;
    f32x4 zf = {0.f,0.f,0.f,0.f};
    f32x4 acc[4] = {zf,zf,zf,zf};
    const unsigned short* arow = xb + (size_t)(m0+16*w+l15)*256 + 8*g;
#pragma unroll
    for (int kk = 0; kk < 8; ++kk) {
        bf16x8 af = *(const bf16x8*)(arow + kk*32);
#pragma unroll
        for (int nt = 0; nt < 4; ++nt) {
            bf16x8 bf = *(const bf16x8*)(W + (size_t)(n0+16*nt+l15)*256 + kk*32 + 8*g);
            acc[nt] = __builtin_amdgcn_mfma_f32_16x16x32_bf16(af, bf, acc[nt], 0, 0, 0);
        }
    }
    int bs_base = m0 + 16*w + 4*g;
#pragma unroll
    for (int nt = 0; nt < 4; ++nt) {
        int col = n0 + 16*nt + l15;             // h*32 + kk
        int h = col>>5, kk = col&31;
#pragma unroll
        for (int j = 0; j < 4; ++j) {
            int bs = bs_base + j;
            int b = bs>>10, s = bs&1023;
            float z = acc[nt][j];
            z = z > 0.f ? z + 1.f : expf(z);
            size_t idx = ((size_t)(h*PB+b)*PS + s)*PK + kk;
            if (isK) { Kf[idx] = z; Kb[idx] = f2bf(z); }
            else     { Q[idx]  = z; Qb[idx] = f2bf(z); }
        }
    }
}

// ---------------- kernel 2: cumsum of K' over s ------------------------------
__global__ void k_cumsum(const float* __restrict__ Kf, float* __restrict__ cumK) {
    int hb  = blockIdx.x;
    int tid = threadIdx.x;
    int c = tid >> 5, kk = tid & 31;
    const float* src = Kf   + hb*(PS*PK) + c*128*PK + kk;
    float*       dst = cumK + hb*(PS*PK) + c*128*PK + kk;
    float sum = 0.f;
#pragma unroll 8
    for (int i = 0; i < 128; ++i) sum += src[i*PK];
    __shared__ float ssum[8][32];
    ssum[c][kk] = sum;
    __syncthreads();
    float acc = 0.f;
    for (int j = 0; j < c; ++j) acc += ssum[j][kk];
#pragma unroll 8
    for (int i = 0; i < 128; ++i) { acc += src[i*PK]; dst[i*PK] = acc; }
}

// ---------------- kernel 3: den[hb,s] = q . cumK + EPS -----------------------
__global__ void k_den(const float* __restrict__ Q, const float* __restrict__ cumK,
                      float* __restrict__ den) {
    int i = blockIdx.x*256 + threadIdx.x;
    const float4* q  = (const float4*)(Q    + (size_t)i*PK);
    const float4* ck = (const float4*)(cumK + (size_t)i*PK);
    float acc = 0.f;
#pragma unroll
    for (int j = 0; j < 8; ++j) {
        float4 a = q[j], b = ck[j];
        acc += a.x*b.x + a.y*b.y + a.z*b.z + a.w*b.w;
    }
    den[i] = acc + EPS;
}

// ---------------- kernel 4: V projection via MFMA -> Vt bf16 -----------------
// Vt layout: [h*32 + bsTile][e 256][t 64] bf16.
__global__ __launch_bounds__(256) void k_proj_v_mfma(
    const unsigned short* __restrict__ xb, const unsigned short* __restrict__ WvT,
    unsigned short* __restrict__ Vt)
{
    int e0 = blockIdx.x*64, m0 = blockIdx.y*64, h = blockIdx.z;
    int tid = threadIdx.x, w = tid>>6, l15 = tid&15, g = (tid>>4)&3;
    f32x4 zf = {0.f,0.f,0.f,0.f};
    f32x4 acc[4] = {zf,zf,zf,zf};
    const unsigned short* arow = xb + (size_t)(m0+16*w+l15)*256 + 8*g;
    const unsigned short* Wb = WvT + (size_t)h*65536;
#pragma unroll
    for (int kk = 0; kk < 8; ++kk) {
        bf16x8 af = *(const bf16x8*)(arow + kk*32);
#pragma unroll
        for (int nt = 0; nt < 4; ++nt) {
            bf16x8 bf = *(const bf16x8*)(Wb + (size_t)(e0+16*nt+l15)*256 + kk*32 + 8*g);
            acc[nt] = __builtin_amdgcn_mfma_f32_16x16x32_bf16(af, bf, acc[nt], 0, 0, 0);
        }
    }
    unsigned short* VtT = Vt + ((size_t)h*32 + blockIdx.y)*(256*64);
#pragma unroll
    for (int nt = 0; nt < 4; ++nt) {
        ushort4 o = {f2bf(acc[nt][0]), f2bf(acc[nt][1]), f2bf(acc[nt][2]), f2bf(acc[nt][3])};
        *(ushort4*)(VtT + (size_t)(e0+16*nt+l15)*64 + 16*w + 4*g) = o;
    }
}

// ---------------- kernel 5: zero-fill strictly-upper att tiles ---------------
__global__ void k_att_zero(float* __restrict__ att) {
    int st = blockIdx.x;           // 0..14
    int hb = blockIdx.y;
    int s0 = st * 64;
    int c0 = s0 + 64;
    int nz4 = (PS - c0) >> 2;
    float* base = att + (size_t)hb*PS*PS + (size_t)s0*PS + c0;
    int r = threadIdx.x >> 2;
    int l4 = threadIdx.x & 3;
    float4 z = {0.f, 0.f, 0.f, 0.f};
    for (int c4 = l4; c4 < nz4; c4 += 4)
        *(float4*)(base + (size_t)r*PS + c4*4) = z;
}

// ---------------- kernel 6: strictly-lower att tiles (uniform, parallel) -----
__global__ __launch_bounds__(256) void k_att_low(
    const unsigned short* __restrict__ Qb, const unsigned short* __restrict__ Kb,
    const float* __restrict__ den, float* __restrict__ att)
{
    int tt = blockIdx.x, st = blockIdx.y, hb = blockIdx.z;
    if (tt >= st) return;                       // diag handled by k_node
    int s0 = st*64, t0 = tt*64;
    int tid = threadIdx.x, w = tid>>6, l15 = tid&15, g = (tid>>4)&3;
    f32x4 zf = {0.f,0.f,0.f,0.f};
    bf16x8 qf = *(const bf16x8*)(Qb + ((size_t)hb*PS + s0 + 16*w + l15)*PK + 8*g);
    f32x4 p[4];
#pragma unroll
    for (int nt = 0; nt < 4; ++nt) {
        bf16x8 kf = *(const bf16x8*)(Kb + ((size_t)hb*PS + t0 + 16*nt + l15)*PK + 8*g);
        p[nt] = __builtin_amdgcn_mfma_f32_16x16x32_bf16(qf, kf, zf, 0, 0, 0);
    }
    float* attb = att + (size_t)hb*PS*PS;
    float rd[4];
#pragma unroll
    for (int j = 0; j < 4; ++j) rd[j] = 1.0f / den[hb*PS + s0 + 16*w + 4*g + j];
#pragma unroll
    for (int nt = 0; nt < 4; ++nt)
#pragma unroll
        for (int j = 0; j < 4; ++j)
            attb[(size_t)(s0 + 16*w + 4*g + j)*PS + t0 + 16*nt + l15] = p[nt][j] * rd[j];
}

// ---------------- kernel 7: per-chunk KV sums --------------------------------
// KVs[hb*16+c][e 256][k 32] f32 = sum_{t in chunk c} Vt[e][t] * K'[t][k]
__global__ __launch_bounds__(256) void k_kv_sums(
    const unsigned short* __restrict__ Kb, const unsigned short* __restrict__ Vt,
    float* __restrict__ KVs)
{
    int c = blockIdx.x, hb = blockIdx.y;
    int tid = threadIdx.x, w = tid>>6, l15 = tid&15, g = (tid>>4)&3;
    __shared__ unsigned short KT[32*72];        // K'^T [kk][t]
#pragma unroll
    for (int i = 0; i < 8; ++i) {
        int flat = tid + i*256;                 // t = flat>>5, k = flat&31
        KT[(flat&31)*72 + (flat>>5)] = Kb[((size_t)hb*PS + c*64 + (flat>>5))*PK + (flat&31)];
    }
    __syncthreads();
    const unsigned short* Vtt = Vt + ((size_t)hb*16 + c)*(256*64);
    f32x4 zf = {0.f,0.f,0.f,0.f};
    f32x4 acc[4][2];
#pragma unroll
    for (int mt = 0; mt < 4; ++mt) { acc[mt][0] = zf; acc[mt][1] = zf; }
#pragma unroll
    for (int ks = 0; ks < 2; ++ks) {
        bf16x8 af[4];
#pragma unroll
        for (int mt = 0; mt < 4; ++mt)
            af[mt] = *(const bf16x8*)(Vtt + (size_t)(64*w + 16*mt + l15)*64 + 32*ks + 8*g);
#pragma unroll
        for (int nt = 0; nt < 2; ++nt) {
            bf16x8 bf = *(const bf16x8*)(KT + (16*nt + l15)*72 + 32*ks + 8*g);
#pragma unroll
            for (int mt = 0; mt < 4; ++mt)
                acc[mt][nt] = __builtin_amdgcn_mfma_f32_16x16x32_bf16(af[mt], bf, acc[mt][nt], 0, 0, 0);
        }
    }
    float* o = KVs + ((size_t)hb*16 + c)*8192;
#pragma unroll
    for (int mt = 0; mt < 4; ++mt)
#pragma unroll
        for (int nt = 0; nt < 2; ++nt)
#pragma unroll
            for (int j = 0; j < 4; ++j)
                o[(size_t)(64*w + 16*mt + 4*g + j)*32 + 16*nt + l15] = acc[mt][nt][j];
}

// ---------------- kernel 8: exclusive scan of KV over chunks -> bf16 ---------
__global__ void k_kv_scan(const float* __restrict__ KVs, unsigned short* __restrict__ KVpre) {
    int hb = blockIdx.y;
    int i = blockIdx.x*256 + threadIdx.x;       // 0..8191 = e*32+k
    const float* src = KVs + (size_t)hb*16*8192 + i;
    unsigned short* dst = KVpre + (size_t)hb*16*8192 + i;
    float acc = 0.f;
#pragma unroll
    for (int c = 0; c < 16; ++c) { dst[c*8192] = f2bf(acc); acc += src[c*8192]; }
}

// ---------------- kernel 9: node = rden*(q.KVpre) + att_diag@V ---------------
// also writes the diagonal att tiles. grid (chunk 16, hb 16).
__global__ __launch_bounds__(256) void k_node(
    const unsigned short* __restrict__ Qb, const unsigned short* __restrict__ Kb,
    const float* __restrict__ den, const unsigned short* __restrict__ Vt,
    const unsigned short* __restrict__ KVpre,
    float* __restrict__ att, unsigned short* __restrict__ nodeB)
{
    int c = blockIdx.x, hb = blockIdx.y;
    int s0 = c*64;
    int tid = threadIdx.x, w = tid>>6, l15 = tid&15, g = (tid>>4)&3;
    __shared__ unsigned short PL[64*72];
    __shared__ float rden[64];
    if (tid < 64) rden[tid] = 1.0f / den[hb*PS + s0 + tid];

    f32x4 zf = {0.f,0.f,0.f,0.f};
    bf16x8 qf = *(const bf16x8*)(Qb + ((size_t)hb*PS + s0 + 16*w + l15)*PK + 8*g);

    // prior: acc[nt] = q . KVpre  (e-tile nt)
    const unsigned short* KVp = KVpre + ((size_t)hb*16 + c)*8192;
    f32x4 acc[16];
#pragma unroll
    for (int nt = 0; nt < 16; ++nt) {
        bf16x8 bf = *(const bf16x8*)(KVp + (size_t)(16*nt + l15)*32 + 8*g);
        acc[nt] = __builtin_amdgcn_mfma_f32_16x16x32_bf16(qf, bf, zf, 0, 0, 0);
    }
    // diagonal P tile
    f32x4 p[4];
#pragma unroll
    for (int nt4 = 0; nt4 < 4; ++nt4) {
        bf16x8 kf = *(const bf16x8*)(Kb + ((size_t)hb*PS + s0 + 16*nt4 + l15)*PK + 8*g);
        p[nt4] = __builtin_amdgcn_mfma_f32_16x16x32_bf16(qf, kf, zf, 0, 0, 0);
    }
    __syncthreads();                            // rden ready
    float* attb = att + (size_t)hb*PS*PS;
#pragma unroll
    for (int nt4 = 0; nt4 < 4; ++nt4) {
#pragma unroll
        for (int j = 0; j < 4; ++j) {
            int r = 16*w + 4*g + j;
            int tc = 16*nt4 + l15;
            float v = p[nt4][j] * rden[r];
            if (tc > r) v = 0.f;
            attb[(size_t)(s0 + r)*PS + s0 + tc] = v;
            PL[r*72 + tc] = f2bf(v);
        }
    }
    // scale prior by rden
#pragma unroll
    for (int nt = 0; nt < 16; ++nt)
#pragma unroll
        for (int j = 0; j < 4; ++j)
            acc[nt][j] *= rden[16*w + 4*g + j];
    __syncthreads();                            // PL ready
    // PV: wave w = m-strip w (rows 16w..16w+15), A = PL, B = Vt[e][t]
    const unsigned short* Vtt = Vt + ((size_t)hb*16 + c)*(256*64);
#pragma unroll
    for (int ks = 0; ks < 2; ++ks) {
        bf16x8 af = *(const bf16x8*)(PL + (size_t)(16*w + l15)*72 + 32*ks + 8*g);
#pragma unroll
        for (int nt = 0; nt < 16; ++nt) {
            bf16x8 vf = *(const bf16x8*)(Vtt + (size_t)(16*nt + l15)*64 + 32*ks + 8*g);
            acc[nt] = __builtin_amdgcn_mfma_f32_16x16x32_bf16(af, vf, acc[nt], 0, 0, 0);
        }
    }
    // store nodeB bf16 [bs][h*256+e]
    int h = hb >> 1, b = hb & 1;
    unsigned short* np = nodeB + ((size_t)(b*PS + s0))*2048 + h*256;
#pragma unroll
    for (int nt = 0; nt < 16; ++nt)
#pragma unroll
        for (int j = 0; j < 4; ++j)
            np[(size_t)(16*w + 4*g + j)*2048 + 16*nt + l15] = f2bf(acc[nt][j]);
}

// ---------------- kernel 10: out = nodeB @ WoT (full K, direct store) --------
__global__ __launch_bounds__(256) void k_out2(
    const unsigned short* __restrict__ nodeB, const unsigned short* __restrict__ WoT,
    float* __restrict__ out)
{
    int e0 = blockIdx.x*64, m0 = blockIdx.y*16;
    int tid = threadIdx.x, w = tid>>6, l15 = tid&15, g = (tid>>4)&3;
    f32x4 zf = {0.f,0.f,0.f,0.f};
    f32x4 acc = zf;
    const unsigned short* arow = nodeB + (size_t)(m0 + l15)*2048 + 8*g;
    const unsigned short* brow = WoT + (size_t)(e0 + 16*w + l15)*2048 + 8*g;
#pragma unroll 8
    for (int kk = 0; kk < 64; ++kk) {
        bf16x8 af = *(const bf16x8*)(arow + kk*32);
        bf16x8 bf = *(const bf16x8*)(brow + kk*32);
        acc = __builtin_amdgcn_mfma_f32_16x16x32_bf16(af, bf, acc, 0, 0, 0);
    }
#pragma unroll
    for (int j = 0; j < 4; ++j)
        out[(size_t)(m0 + 4*g + j)*PD + e0 + 16*w + l15] = acc[j];
}

// ---------------- launch ------------------------------------------------------
extern "C" void kernel_launch(void* const* d_in, const int* in_sizes, int n_in,
                              void* d_out, int out_size, void* d_ws, size_t ws_size,
                              hipStream_t stream) {
    const float* x   = (const float*)d_in[0];
    const float* Wks = (const float*)d_in[1];
    const float* Wqs = (const float*)d_in[2];
    const float* Wvs = (const float*)d_in[3];
    const float* Wo  = (const float*)d_in[4];

    float* out = (float*)d_out;                     // [B,S,D]
    float* att = (float*)d_out + (size_t)PB*PS*PD;  // [H,B,S,S]

    // workspace layout (float offsets)
    // region0 (2,097,152 f): Q@0, Kf@524288, cumK@1048576 early;
    //   reused by KVs (full region) after k_den.
    float* ws = (float*)d_ws;
    float*          Q     = ws + 0;
    float*          Kf    = ws + 524288;
    float*          cumK  = ws + 1048576;
    float*          KVs   = ws + 0;                            // reuse region0
    float*          den   = ws + 2097152;   //    16,384
    unsigned short* Qb    = (unsigned short*)(ws + 2113536);   //   524,288 u16
    unsigned short* Kb    = (unsigned short*)(ws + 2375680);   //   524,288 u16
    unsigned short* Vt    = (unsigned short*)(ws + 2637824);   // 4,194,304 u16
    unsigned short* xb    = (unsigned short*)(ws + 4734976);   //   524,288 u16
    unsigned short* WqT   = (unsigned short*)(ws + 4997120);   //    65,536 u16
    unsigned short* WkT   = (unsigned short*)(ws + 5029888);   //    65,536 u16
    unsigned short* WvT   = (unsigned short*)(ws + 5062656);   //   524,288 u16
    unsigned short* WoT   = (unsigned short*)(ws + 5324800);   //   524,288 u16
    unsigned short* nodeB = (unsigned short*)(ws + 5586944);   // 4,194,304 u16
    unsigned short* KVpre = (unsigned short*)(ws + 7684096);   // 2,097,152 u16
    const size_t needed = (size_t)8732672 * 4;
    if (ws_size < needed) {
        fprintf(stderr, "kernel_launch: ws_size %zu < needed %zu\n", ws_size, needed);
        return;
    }

    k_xb<<<512, 256, 0, stream>>>(x, xb);
    k_transpose_qk<<<dim3(PH, 2), 256, 0, stream>>>(Wqs, Wks, WqT, WkT);
    k_transpose256<<<dim3(4, 4, PH), 256, 0, stream>>>(Wvs, WvT, 256, 65536);
    k_transpose256<<<dim3(4, 4, PH), 256, 0, stream>>>(Wo,  WoT, 2048, 256);
    k_proj_qk_mfma<<<dim3(32, 2, 4), 256, 0, stream>>>(xb, WqT, WkT, Q, Kf, Qb, Kb);
    k_cumsum<<<HB, 256, 0, stream>>>(Kf, cumK);
    k_den<<<64, 256, 0, stream>>>(Q, cumK, den);
    k_proj_v_mfma<<<dim3(4, 32, PH), 256, 0, stream>>>(xb, WvT, Vt);
    k_att_zero<<<dim3(15, HB), 256, 0, stream>>>(att);
    k_att_low<<<dim3(16, 16, HB), 256, 0, stream>>>(Qb, Kb, den, att);
    k_kv_sums<<<dim3(16, HB), 256, 0, stream>>>(Kb, Vt, KVs);      // overwrites Q/Kf/cumK (dead)
    k_kv_scan<<<dim3(32, HB), 256, 0, stream>>>(KVs, KVpre);
    k_node<<<dim3(16, HB), 256, 0, stream>>>(Qb, Kb, den, Vt, KVpre, att, nodeB);
    k_out2<<<dim3(4, 128), 256, 0, stream>>>(nodeB, WoT, out);
}